// Round 12
// baseline (368.492 us; speedup 1.0000x reference)
//
#include <hip/hip_runtime.h>
#include <stdint.h>

#define NB 262144
#define D 128
#define K 10

#define ROWS_PER_BLOCK 128
#define QBLOCKS (NB / ROWS_PER_BLOCK)   // 2048
#define QTHREADS 256

typedef __attribute__((ext_vector_type(8))) __bf16 bf16x8;
typedef __attribute__((ext_vector_type(4))) float f32x4;

__device__ inline bf16x8 make_frag(const float4 lo, const float4 hi) {
  bf16x8 a;
  a[0] = (__bf16)lo.x; a[1] = (__bf16)lo.y; a[2] = (__bf16)lo.z; a[3] = (__bf16)lo.w;
  a[4] = (__bf16)hi.x; a[5] = (__bf16)hi.y; a[6] = (__bf16)hi.z; a[7] = (__bf16)hi.w;
  return a;
}

// ---------------- Kernel 1: q + column partial sums (R9, unchanged) --------
__global__ __launch_bounds__(QTHREADS) void qkern(
    const float* __restrict__ z, const float* __restrict__ centers,
    float* __restrict__ qout, float* __restrict__ f) {
  __shared__ float red[4][16];

  const int t = threadIdx.x;
  const int w = t >> 6;
  const int lane = t & 63;
  const int n = lane & 15;
  const int g = lane >> 4;

  bf16x8 afrag[4];
  float mu2own = 0.f;
  if (n < K) {
    const float* cp = centers + n * D;
#pragma unroll
    for (int c = 0; c < 4; ++c) {
      float4 lo = *reinterpret_cast<const float4*>(cp + c * 32 + g * 8);
      float4 hi = *reinterpret_cast<const float4*>(cp + c * 32 + g * 8 + 4);
      afrag[c] = make_frag(lo, hi);
    }
#pragma unroll
    for (int d4 = 0; d4 < 32; ++d4) {
      float4 v = *reinterpret_cast<const float4*>(cp + d4 * 4);
      mu2own = fmaf(v.x, v.x, mu2own); mu2own = fmaf(v.y, v.y, mu2own);
      mu2own = fmaf(v.z, v.z, mu2own); mu2own = fmaf(v.w, v.w, mu2own);
    }
  } else {
    unsigned short zb = 0;
#pragma unroll
    for (int c = 0; c < 4; ++c)
#pragma unroll
      for (int j = 0; j < 8; ++j) afrag[c][j] = __builtin_bit_cast(__bf16, zb);
  }
  float mu2[4];
#pragma unroll
  for (int i = 0; i < 4; ++i) mu2[i] = __shfl(mu2own, g * 4 + i);

  float colp[4] = {0.f, 0.f, 0.f, 0.f};
  const int wbase = blockIdx.x * ROWS_PER_BLOCK + w * 32;

#pragma unroll
  for (int tile = 0; tile < 2; ++tile) {
    const int rbase = wbase + tile * 16;
    const float* zr = z + (size_t)(rbase + n) * D + g * 8;

    float4 zf[8];
#pragma unroll
    for (int c = 0; c < 4; ++c) {
      zf[2 * c]     = *reinterpret_cast<const float4*>(zr + c * 32);
      zf[2 * c + 1] = *reinterpret_cast<const float4*>(zr + c * 32 + 4);
    }

    float z2 = 0.f;
#pragma unroll
    for (int q8 = 0; q8 < 8; ++q8) {
      z2 = fmaf(zf[q8].x, zf[q8].x, z2); z2 = fmaf(zf[q8].y, zf[q8].y, z2);
      z2 = fmaf(zf[q8].z, zf[q8].z, z2); z2 = fmaf(zf[q8].w, zf[q8].w, z2);
    }
    z2 += __shfl_xor(z2, 16);
    z2 += __shfl_xor(z2, 32);

    f32x4 acc = {0.f, 0.f, 0.f, 0.f};
#pragma unroll
    for (int c = 0; c < 4; ++c) {
      bf16x8 b = make_frag(zf[2 * c], zf[2 * c + 1]);
      acc = __builtin_amdgcn_mfma_f32_16x16x32_bf16(afrag[c], b, acc, 0, 0, 0);
    }

    float qu[4];
    float s = 0.f;
#pragma unroll
    for (int i = 0; i < 4; ++i) {
      const int cl = g * 4 + i;
      float d2 = z2 - 2.f * acc[i] + mu2[i];
      qu[i] = (cl < K) ? 1.0f / (1.0f + d2) : 0.f;
      s += qu[i];
    }
    s += __shfl_xor(s, 16);
    s += __shfl_xor(s, 32);
    float inv = 1.0f / s;
#pragma unroll
    for (int i = 0; i < 4; ++i) { qu[i] *= inv; colp[i] += qu[i]; }

    float* qo = qout + (size_t)(rbase + n) * K;
    if (g < 2)
      *reinterpret_cast<float4*>(qo + g * 4) = make_float4(qu[0], qu[1], qu[2], qu[3]);
    else if (g == 2)
      *reinterpret_cast<float2*>(qo + 8) = make_float2(qu[0], qu[1]);
  }

#pragma unroll
  for (int i = 0; i < 4; ++i) {
    colp[i] += __shfl_xor(colp[i], 1);
    colp[i] += __shfl_xor(colp[i], 2);
    colp[i] += __shfl_xor(colp[i], 4);
    colp[i] += __shfl_xor(colp[i], 8);
  }
  if (n == 0) {
#pragma unroll
    for (int i = 0; i < 4; ++i) red[w][g * 4 + i] = colp[i];
  }
  __syncthreads();
  if (t < K) atomicAdd(&f[t], red[0][t] + red[1][t] + red[2][t] + red[3][t]);
}

// ---------------- Kernel 2: p from q, f (unchanged) ----------------
__global__ __launch_bounds__(256) void pkern(
    const float* __restrict__ q, const float* __restrict__ f,
    float* __restrict__ p) {
  int row = blockIdx.x * 256 + threadIdx.x;
  const float* qr = q + (size_t)row * K;
  float wv[K];
  float s = 0.f;
#pragma unroll
  for (int j = 0; j < K; j += 2) {
    float2 qq = *reinterpret_cast<const float2*>(&qr[j]);
    wv[j] = qq.x * qq.x / f[j];
    wv[j + 1] = qq.y * qq.y / f[j + 1];
    s += wv[j] + wv[j + 1];
  }
  float inv = 1.0f / s;
  float* pr = p + (size_t)row * K;
#pragma unroll
  for (int j = 0; j < K; j += 2) {
    *reinterpret_cast<float2*>(&pr[j]) = make_float2(wv[j] * inv, wv[j + 1] * inv);
  }
}

// ---------------- Probe: pure coalesced read of z, 4 passes ----------------
// MEASUREMENT ONLY (output goes to scratch). Grid-stride float4 sweep:
// each wave-instruction reads 1 KB contiguous (fill-like best case).
// 4 passes x 134 MB = 536 MB read; lands in rocprof top-5 in both the
// fast (>=5 TB/s -> ~90us) and slow (~2 TB/s -> ~240us) outcomes.
__global__ __launch_bounds__(256) void zread_probe(
    const float4* __restrict__ z4, float* __restrict__ sink) {
  const size_t n4 = (size_t)NB * D / 4;            // 33,554,432
  const size_t stride = (size_t)gridDim.x * 256;
  const size_t gid = (size_t)blockIdx.x * 256 + threadIdx.x;
  float4 acc = {0.f, 0.f, 0.f, 0.f};
  for (int pass = 0; pass < 4; ++pass) {
    for (size_t i = gid; i < n4; i += stride) {
      float4 v = z4[i];
      acc.x += v.x; acc.y += v.y; acc.z += v.z; acc.w += v.w;
    }
  }
  float s = acc.x + acc.y + acc.z + acc.w;
  s += __shfl_xor(s, 1);  s += __shfl_xor(s, 2);  s += __shfl_xor(s, 4);
  s += __shfl_xor(s, 8);  s += __shfl_xor(s, 16); s += __shfl_xor(s, 32);
  if ((threadIdx.x & 63) == 0) atomicAdd(sink, s);
}

extern "C" void kernel_launch(void* const* d_in, const int* in_sizes, int n_in,
                              void* d_out, int out_size, void* d_ws, size_t ws_size,
                              hipStream_t stream) {
  const float* z = (const float*)d_in[0];
  const float* centers = (const float*)d_in[1];
  float* out = (float*)d_out;            // q at [0, NB*K), p at [NB*K, 2*NB*K)
  float* f = (float*)d_ws;               // K column sums
  float* sink = (float*)d_ws + 64;       // probe scratch

  hipMemsetAsync(d_ws, 0, 65 * sizeof(float), stream);
  qkern<<<QBLOCKS, QTHREADS, 0, stream>>>(z, centers, out, f);
  pkern<<<NB / 256, 256, 0, stream>>>(out, f, out + (size_t)NB * K);
  zread_probe<<<2048, 256, 0, stream>>>((const float4*)z, sink);
}